// Round 12
// baseline (2625.867 us; speedup 1.0000x reference)
//
#include <hip/hip_runtime.h>
#include <hip/hip_bf16.h>
#include <stdint.h>

typedef _Float16 f16x8 __attribute__((ext_vector_type(8)));
typedef _Float16 f16x4 __attribute__((ext_vector_type(4)));
typedef float    f32x4 __attribute__((ext_vector_type(4)));

#define NT  48
#define NTU 32

// ---------------------------------------------------------------------------
// global->LDS direct load, 16B per lane; LDS dest = wave-uniform base + lane*16
// ---------------------------------------------------------------------------
__device__ __forceinline__ void gload_lds16(const void* g, void* l) {
  __builtin_amdgcn_global_load_lds(
      reinterpret_cast<const __attribute__((address_space(1))) void*>(
          reinterpret_cast<uintptr_t>(g)),
      reinterpret_cast<__attribute__((address_space(3))) void*>(
          reinterpret_cast<uintptr_t>(l)),
      16, 0, 0);
}

// XOR swizzle within each 128B row, keyed off row&7 (bits 7-9 of byte offset).
__device__ __forceinline__ int swz(int o) { return o ^ ((o >> 3) & 0x70); }

// ---------------------------------------------------------------------------
// merged prepass kernel (identical to r11, verified):
//   [0, 65536)      : cvt union_features f32 -> f16
//   [65536, 66560)  : Wpc -> Btc fragment-major
//   [66560, 68608)  : Wup -> Btu fragment-major
//   [68608, 68768)  : edge_rep = f16(relu(edge_ctx @ Wpe + bpe))
// ---------------------------------------------------------------------------
__global__ __launch_bounds__(256) void k_pre(
    const float* __restrict__ uf,  _Float16* __restrict__ Auf,
    const float* __restrict__ Wpc, _Float16* __restrict__ Btc,
    const float* __restrict__ Wup, _Float16* __restrict__ Btu,
    const float* __restrict__ ec,  const float* __restrict__ Wpe,
    const float* __restrict__ bpe, _Float16* __restrict__ er)
{
  __shared__ float lds_f[64 * 65];
  const int b = blockIdx.x;
  const int t = threadIdx.x;

  if (b < 65536) {
    const size_t g = (size_t)b * 256 + t;
    const f32x4* p = reinterpret_cast<const f32x4*>(uf) + g * 2;
    f32x4 v0 = p[0], v1 = p[1];
    f16x8 h;
    h[0] = (_Float16)v0[0]; h[1] = (_Float16)v0[1];
    h[2] = (_Float16)v0[2]; h[3] = (_Float16)v0[3];
    h[4] = (_Float16)v1[0]; h[5] = (_Float16)v1[1];
    h[6] = (_Float16)v1[2]; h[7] = (_Float16)v1[3];
    *(reinterpret_cast<f16x8*>(Auf) + g) = h;
    return;
  }

  if (b < 68608) {
    const float* W; _Float16* Bf; int K, bid2;
    if (b < 66560) { W = Wpc; Bf = Btc; K = 1024; bid2 = b - 65536; }
    else           { W = Wup; Bf = Btu; K = 2048; bid2 = b - 66560; }
    const int ntn = 64;
    const int kt = bid2 / ntn, nt = bid2 % ntn;
    const int tx = t & 63, ty = t >> 6;
    const int k0 = kt * 64, n0 = nt * 64;
    const int KB = K >> 5;
#pragma unroll
    for (int j = 0; j < 16; ++j) {
      int kr = j * 4 + ty;
      lds_f[kr * 65 + tx] = W[(size_t)(k0 + kr) * 4096 + n0 + tx];
    }
    __syncthreads();
#pragma unroll
    for (int p = 0; p < 2; ++p) {
      int c    = p * 256 + t;
      int g16l = c >> 7;
      int kbl  = (c >> 6) & 1;
      int l    = c & 63;
      f16x8 h;
#pragma unroll
      for (int j = 0; j < 8; ++j)
        h[j] = (_Float16)lds_f[(kbl * 32 + (l >> 4) * 8 + j) * 65 + g16l * 16 + (l & 15)];
      size_t g16 = (size_t)((n0 >> 4) + g16l);
      size_t kb  = (size_t)((k0 >> 5) + kbl);
      *reinterpret_cast<f16x8*>(Bf + ((g16 * KB + kb) * 64 + l) * 8) = h;
    }
    return;
  }

  {
    const int rb = (b - 68608) * 8;
    float* sec = lds_f;
#pragma unroll
    for (int j = 0; j < 16; ++j)
      sec[j * 256 + t] = ec[(size_t)rb * 512 + j * 256 + t];
    __syncthreads();

    const int c4 = t * 4;
    f32x4 acc[8];
#pragma unroll
    for (int r = 0; r < 8; ++r) acc[r] = f32x4{0.f, 0.f, 0.f, 0.f};
    for (int k = 0; k < 512; ++k) {
      f32x4 w = *reinterpret_cast<const f32x4*>(Wpe + (size_t)k * 1024 + c4);
#pragma unroll
      for (int r = 0; r < 8; ++r) acc[r] += sec[r * 512 + k] * w;
    }
    f32x4 bb = *reinterpret_cast<const f32x4*>(bpe + c4);
#pragma unroll
    for (int r = 0; r < 8; ++r) {
      f32x4 o = acc[r] + bb;
      f16x4 h;
#pragma unroll
      for (int i = 0; i < 4; ++i) h[i] = (_Float16)(o[i] > 0.f ? o[i] : 0.f);
      *reinterpret_cast<f16x4*>(er + (size_t)(rb + r) * 1024 + c4) = h;
    }
  }
}

// ---------------------------------------------------------------------------
// A staging: NI chunks of 8KB; linear LDS dest, source pre-swizzled.
// ---------------------------------------------------------------------------
template<int NI>
__device__ __forceinline__ void stage_tile(const _Float16* __restrict__ src, int ldk,
                                           int rcBase, int kt, _Float16* sbuf, int tid)
{
#pragma unroll
  for (int j = 0; j < NI; ++j) {
    int o  = j * 8192 + tid * 16;
    int op = swz(o);
    int r  = op >> 7;
    int kh = (op & 127) >> 1;
    gload_lds16(src + (size_t)(rcBase + r) * ldk + kt + kh,
                sbuf + (o - (tid & 63) * 16) / 2);
  }
}

// B fragment load: 8 coalesced dwordx4 (one MFMA B-operand per load).
__device__ __forceinline__ void load_bfrag(const f16x8* __restrict__ BfU,
                                           const f16x8* __restrict__ BfC,
                                           const int* g16, int lane, int tt,
                                           f16x8 (&bf)[4][2])
{
  if (tt < NTU) {
#pragma unroll
    for (int n = 0; n < 4; ++n)
#pragma unroll
      for (int ks = 0; ks < 2; ++ks)
        bf[n][ks] = BfU[((size_t)g16[n] * 64 + tt * 2 + ks) * 64 + lane];
  } else {
    const int tc = tt - NTU;
#pragma unroll
    for (int n = 0; n < 4; ++n)
#pragma unroll
      for (int ks = 0; ks < 2; ++ks)
        bf[n][ks] = BfC[((size_t)g16[n] * 32 + tc * 2 + ks) * 64 + lane];
  }
}

// ---------------------------------------------------------------------------
// main fused dual-GEMM: out = (Acat@Wc^T + bc) * (Auf@Wu^T + bu)
// BM=256 BN=128 BK=64, 512 thr = 8 waves (4x2), wave tile 64x64.
// A: LDS 3-buffer depth-2; B: direct L2 -> regs (fragment-major), double-buf.
// FIFO-calibrated waits: per body issue B(t+1) [8] THEN A(t+2) [4]; queue at
// tile top = A(t)4 | B(t)8 | A(t+1)4 -> manual vmcnt(4) retires exactly
// {A(t), B(t)}, keeps A(t+1) in flight. One barrier/tile, unfenced interior.
// ---------------------------------------------------------------------------
__global__ __launch_bounds__(512, 2) void k_main(
    const _Float16* __restrict__ er,  const int* __restrict__ pidx,
    const _Float16* __restrict__ Auf,
    const _Float16* __restrict__ Btc, const _Float16* __restrict__ Btu,
    const float* __restrict__ bcat, const float* __restrict__ bup,
    float* __restrict__ out)
{
  extern __shared__ char smem[];                    // 96 KiB: 3 x 32KB A
  _Float16* bufA[3] = { reinterpret_cast<_Float16*>(smem),
                        reinterpret_cast<_Float16*>(smem + 32768),
                        reinterpret_cast<_Float16*>(smem + 65536) };

  const int tid  = threadIdx.x;
  const int lane = tid & 63, lr = lane & 15, lg = lane >> 4;
  const int wid  = tid >> 6, wr = wid >> 1, wc = wid & 1;      // 4x2 wave grid

  // XCD column-ownership mapping
  const int bid = blockIdx.x;
  const int xcd = bid & 7;
  const int seq = bid >> 3;
  const int rowBase = (seq >> 2) * 256;
  const int colBase = (xcd * 4 + (seq & 3)) * 128;

  // swizzled LDS read offsets (A only)
  const int key  = (lr & 7) << 4;
  int kb[2];
  kb[0] = (lg * 16) ^ key;
  kb[1] = (64 + lg * 16) ^ key;
  const int aoff = (wr * 64 + lr) * 128;

  // B fragment column groups
  int g16[4];
#pragma unroll
  for (int n = 0; n < 4; ++n) g16[n] = (colBase >> 4) + wc * 4 + n;
  const f16x8* BfU = reinterpret_cast<const f16x8*>(Btu);
  const f16x8* BfC = reinterpret_cast<const f16x8*>(Btc);

  // fused-gather source pointers for cat A staging
  const _Float16* catH[4];
  const _Float16* catT[4];
#pragma unroll
  for (int j = 0; j < 4; ++j) {
    int o  = j * 8192 + tid * 16;
    int op = swz(o);
    int r  = op >> 7;
    int kh = (op & 127) >> 1;
    int gr = rowBase + r;
    catH[j] = er + (size_t)pidx[2 * gr]     * 1024 + kh;
    catT[j] = er + (size_t)pidx[2 * gr + 1] * 1024 + kh;
  }

  f16x8 af[4][2], bfA[4][2], bfB[4][2];
  f32x4 accU[4][4] = {};
  f32x4 accP[4][4] = {};

  _Float16 *Ac = bufA[0], *An = bufA[1], *Af = bufA[2];

  // prologue (FIFO order matters): A(0) [4], B(0) [8], A(1) [4]
  stage_tile<4>(Auf, 2048, rowBase, 0, Ac, tid);
  load_bfrag(BfU, BfC, g16, lane, 0, bfA);
  stage_tile<4>(Auf, 2048, rowBase, 64, An, tid);

#define TILE_BODY(T, ACC, BFC_, BFN_)                                          \
  do {                                                                         \
    const int t = (T);                                                         \
    /* queue: A(t)4 | B(t)8 | A(t+1)4 -> retire first 12 */                    \
    if (t < NT - 1) asm volatile("s_waitcnt vmcnt(4)" ::: "memory");           \
    else            asm volatile("s_waitcnt vmcnt(0)" ::: "memory");           \
    __builtin_amdgcn_s_barrier();                                              \
    /* issue B(t+1) FIRST (8 vm ops) */                                        \
    if (t + 1 < NT) load_bfrag(BfU, BfC, g16, lane, t + 1, BFN_);              \
    __builtin_amdgcn_sched_barrier(0);                                         \
    /* then stage A(t+2) (4 vm ops) */                                         \
    if (t + 2 < NT) {                                                          \
      const int tt = t + 2;                                                    \
      if (tt < NTU) stage_tile<4>(Auf, 2048, rowBase, tt * 64, Af, tid);       \
      else {                                                                   \
        const int ktp  = (tt - NTU) * 64;                                      \
        const bool tail = ktp >= 512;                                          \
        char* AfB = reinterpret_cast<char*>(Af);                               \
        _Pragma("unroll") for (int j = 0; j < 4; ++j) {                        \
          int o = j * 8192 + tid * 16;                                         \
          const _Float16* src = (tail ? catT[j] : catH[j]) + ktp;              \
          gload_lds16(src, AfB + (o - lane * 16));                             \
        }                                                                      \
      }                                                                        \
    }                                                                          \
    const char* aB = reinterpret_cast<const char*>(Ac) + aoff;                 \
    _Pragma("unroll") for (int m = 0; m < 4; ++m)                              \
      _Pragma("unroll") for (int ks = 0; ks < 2; ++ks)                         \
        af[m][ks] = *reinterpret_cast<const f16x8*>(aB + m * 2048 + kb[ks]);   \
    _Pragma("unroll") for (int m = 0; m < 4; ++m)                              \
      _Pragma("unroll") for (int n = 0; n < 4; ++n)                            \
        _Pragma("unroll") for (int ks = 0; ks < 2; ++ks)                       \
          ACC[m][n] = __builtin_amdgcn_mfma_f32_16x16x32_f16(af[m][ks], BFC_[n][ks], ACC[m][n], 0, 0, 0); \
    _Float16* tA = Ac; Ac = An; An = Af; Af = tA;                              \
  } while (0)

  for (int tt = 0; tt < NTU; tt += 2) {
    TILE_BODY(tt,     accU, bfA, bfB);
    TILE_BODY(tt + 1, accU, bfB, bfA);
  }
  for (int tt = NTU; tt < NT; tt += 2) {
    TILE_BODY(tt,     accP, bfA, bfB);
    TILE_BODY(tt + 1, accP, bfB, bfA);
  }
#undef TILE_BODY

  // ---------------- epilogue ----------------
#pragma unroll
  for (int n = 0; n < 4; ++n) {
    const int col = colBase + wc * 64 + n * 16 + lr;
    const float bc = bcat[col], bu = bup[col];
#pragma unroll
    for (int m = 0; m < 4; ++m) {
      const int row0 = rowBase + wr * 64 + m * 16 + lg * 4;
#pragma unroll
      for (int i = 0; i < 4; ++i)
        out[(size_t)(row0 + i) * 4096 + col] =
            (accP[m][n][i] + bc) * (accU[m][n][i] + bu);
    }
  }
}

// ---------------------------------------------------------------------------
extern "C" void kernel_launch(void* const* d_in, const int* in_sizes, int n_in,
                              void* d_out, int out_size, void* d_ws, size_t ws_size,
                              hipStream_t stream)
{
  const float* edge_ctx = (const float*)d_in[0];
  const int*   pair_idx = (const int*)d_in[1];
  const float* uf       = (const float*)d_in[2];
  const float* Wpe      = (const float*)d_in[3];
  const float* bpe      = (const float*)d_in[4];
  const float* Wpc      = (const float*)d_in[5];
  const float* bpc      = (const float*)d_in[6];
  const float* Wup      = (const float*)d_in[7];
  const float* bup      = (const float*)d_in[8];
  float* out = (float*)d_out;

  char* ws = (char*)d_ws;
  _Float16* edge_rep = (_Float16*)ws;                                // 2.6 MB region
  _Float16* Auf  = (_Float16*)(ws + 5242880);                        // 256 MB
  _Float16* Btc  = (_Float16*)(ws + 5242880 + 268435456);            //   8 MB
  _Float16* Btu  = (_Float16*)(ws + 5242880 + 268435456 + 8388608);  //  16 MB

  (void)hipFuncSetAttribute((const void*)k_main,
                            hipFuncAttributeMaxDynamicSharedMemorySize, 98304);

  k_pre<<<68768, 256, 0, stream>>>(uf, Auf, Wpc, Btc, Wup, Btu,
                                   edge_ctx, Wpe, bpe, edge_rep);
  k_main<<<8192, 512, 98304, stream>>>(edge_rep, pair_idx, Auf, Btc, Btu,
                                       bpc, bup, out);
}

// Round 13
// 2052.790 us; speedup vs baseline: 1.2792x; 1.2792x over previous
//
#include <hip/hip_runtime.h>
#include <hip/hip_bf16.h>
#include <stdint.h>

typedef _Float16 f16x8 __attribute__((ext_vector_type(8)));
typedef _Float16 f16x4 __attribute__((ext_vector_type(4)));
typedef float    f32x4 __attribute__((ext_vector_type(4)));
typedef float    f32x16 __attribute__((ext_vector_type(16)));

#define NT  48
#define NTU 32

// ---------------------------------------------------------------------------
// global->LDS direct load, 16B per lane; LDS dest = wave-uniform base + lane*16
// ---------------------------------------------------------------------------
__device__ __forceinline__ void gload_lds16(const void* g, void* l) {
  __builtin_amdgcn_global_load_lds(
      reinterpret_cast<const __attribute__((address_space(1))) void*>(
          reinterpret_cast<uintptr_t>(g)),
      reinterpret_cast<__attribute__((address_space(3))) void*>(
          reinterpret_cast<uintptr_t>(l)),
      16, 0, 0);
}

// XOR swizzle within each 128B row, keyed off row&7 (bits 7-9 of byte offset).
__device__ __forceinline__ int swz(int o) { return o ^ ((o >> 3) & 0x70); }

// ---------------------------------------------------------------------------
// merged prepass kernel (r10-verified), role-split by blockIdx:
//   [0, 65536)      : cvt union_features f32 -> f16
//   [65536, 66560)  : transpose Wpc -> Btc row-major (N x K)
//   [66560, 68608)  : transpose Wup -> Btu row-major
//   [68608, 68768)  : edge_rep = f16(relu(edge_ctx @ Wpe + bpe))
// ---------------------------------------------------------------------------
__global__ __launch_bounds__(256) void k_pre(
    const float* __restrict__ uf,  _Float16* __restrict__ Auf,
    const float* __restrict__ Wpc, _Float16* __restrict__ Btc,
    const float* __restrict__ Wup, _Float16* __restrict__ Btu,
    const float* __restrict__ ec,  const float* __restrict__ Wpe,
    const float* __restrict__ bpe, _Float16* __restrict__ er)
{
  __shared__ float lds_f[64 * 65];
  const int b = blockIdx.x;
  const int t = threadIdx.x;

  if (b < 65536) {
    const size_t g = (size_t)b * 256 + t;
    const f32x4* p = reinterpret_cast<const f32x4*>(uf) + g * 2;
    f32x4 v0 = p[0], v1 = p[1];
    f16x8 h;
    h[0] = (_Float16)v0[0]; h[1] = (_Float16)v0[1];
    h[2] = (_Float16)v0[2]; h[3] = (_Float16)v0[3];
    h[4] = (_Float16)v1[0]; h[5] = (_Float16)v1[1];
    h[6] = (_Float16)v1[2]; h[7] = (_Float16)v1[3];
    *(reinterpret_cast<f16x8*>(Auf) + g) = h;
    return;
  }

  if (b < 68608) {
    const float* W; _Float16* Wt; int K, bid2;
    if (b < 66560) { W = Wpc; Wt = Btc; K = 1024; bid2 = b - 65536; }
    else           { W = Wup; Wt = Btu; K = 2048; bid2 = b - 66560; }
    const int ntn = 64;
    const int kt = bid2 / ntn, nt = bid2 % ntn;
    const int tx = t & 63, ty = t >> 6;
    const int k0 = kt * 64, n0 = nt * 64;
#pragma unroll
    for (int j = 0; j < 16; ++j) {
      int kr = j * 4 + ty;
      lds_f[kr * 65 + tx] = W[(size_t)(k0 + kr) * 4096 + n0 + tx];
    }
    __syncthreads();
#pragma unroll
    for (int j = 0; j < 16; ++j) {
      int nr = j * 4 + ty;
      Wt[(size_t)(n0 + nr) * K + k0 + tx] = (_Float16)lds_f[tx * 65 + nr];
    }
    return;
  }

  {
    const int rb = (b - 68608) * 8;
    float* sec = lds_f;
#pragma unroll
    for (int j = 0; j < 16; ++j)
      sec[j * 256 + t] = ec[(size_t)rb * 512 + j * 256 + t];
    __syncthreads();

    const int c4 = t * 4;
    f32x4 acc[8];
#pragma unroll
    for (int r = 0; r < 8; ++r) acc[r] = f32x4{0.f, 0.f, 0.f, 0.f};
    for (int k = 0; k < 512; ++k) {
      f32x4 w = *reinterpret_cast<const f32x4*>(Wpe + (size_t)k * 1024 + c4);
#pragma unroll
      for (int r = 0; r < 8; ++r) acc[r] += sec[r * 512 + k] * w;
    }
    f32x4 bb = *reinterpret_cast<const f32x4*>(bpe + c4);
#pragma unroll
    for (int r = 0; r < 8; ++r) {
      f32x4 o = acc[r] + bb;
      f16x4 h;
#pragma unroll
      for (int i = 0; i < 4; ++i) h[i] = (_Float16)(o[i] > 0.f ? o[i] : 0.f);
      *reinterpret_cast<f16x4*>(er + (size_t)(rb + r) * 1024 + c4) = h;
    }
  }
}

// ---------------------------------------------------------------------------
// A/B staging: NI chunks of 8KB; linear LDS dest, source pre-swizzled.
// ---------------------------------------------------------------------------
template<int NI>
__device__ __forceinline__ void stage_tile(const _Float16* __restrict__ src, int ldk,
                                           int rcBase, int kt, _Float16* sbuf, int tid)
{
#pragma unroll
  for (int j = 0; j < NI; ++j) {
    int o  = j * 8192 + tid * 16;
    int op = swz(o);
    int r  = op >> 7;
    int kh = (op & 127) >> 1;
    gload_lds16(src + (size_t)(rcBase + r) * ldk + kt + kh,
                sbuf + (o - (tid & 63) * 16) / 2);
  }
}

// ---------------------------------------------------------------------------
// main fused dual-GEMM: out = (Acat@Wc^T + bc) * (Auf@Wu^T + bu)
// BM=256 BN=128 BK=64, 512 thr = 8 waves (4x2), wave tile 64x64.
// r10 skeleton (3-buffer, depth-2, vmcnt(6), ONE barrier/tile, XCD-col map,
// unfenced interior, fused cat-gather). MFMA shape: 32x32x16 (2x2 frags,
// f32x16 acc) -> half the MFMA instructions, +15% matrix-pipe ceiling.
// Unified 48-tile K loop: tiles 0..31 = union (K=2048), 32..47 = cat (K=1024).
// ---------------------------------------------------------------------------
__global__ __launch_bounds__(512, 2) void k_main(
    const _Float16* __restrict__ er,  const int* __restrict__ pidx,
    const _Float16* __restrict__ Auf,
    const _Float16* __restrict__ Btc, const _Float16* __restrict__ Btu,
    const float* __restrict__ bcat, const float* __restrict__ bup,
    float* __restrict__ out)
{
  extern __shared__ char smem[];                    // 144 KiB dynamic
  _Float16* bufA[3] = { reinterpret_cast<_Float16*>(smem),
                        reinterpret_cast<_Float16*>(smem + 32768),
                        reinterpret_cast<_Float16*>(smem + 65536) };
  _Float16* bufB[3] = { reinterpret_cast<_Float16*>(smem + 98304),
                        reinterpret_cast<_Float16*>(smem + 98304 + 16384),
                        reinterpret_cast<_Float16*>(smem + 98304 + 32768) };

  const int tid  = threadIdx.x;
  const int lane = tid & 63;
  const int l31  = lane & 31, lh = lane >> 5;
  const int wid  = tid >> 6, wr = wid >> 1, wc = wid & 1;      // 4x2 wave grid

  // XCD column-ownership mapping: xcd = bid&7 owns cols [xcd*512, xcd*512+512)
  const int bid = blockIdx.x;
  const int xcd = bid & 7;
  const int seq = bid >> 3;
  const int rowBase = (seq >> 2) * 256;
  const int colBase = (xcd * 4 + (seq & 3)) * 128;

  // swizzled LDS read offsets for 32x32x16 fragments:
  // frag row = {wr|wc}*64 + m*32 + l31; k-granule = ks*2 + lh (16B each),
  // swizzle key = (row&7)<<4 = (l31&7)<<4.
  const int key32 = (l31 & 7) << 4;
  int kk[4];
#pragma unroll
  for (int ks = 0; ks < 4; ++ks) kk[ks] = (((ks * 2 + lh) << 4) ^ key32);
  const int aoff = (wr * 64 + l31) * 128;
  const int boff = (wc * 64 + l31) * 128;

  // fused-gather source pointers for cat A staging
  const _Float16* catH[4];
  const _Float16* catT[4];
#pragma unroll
  for (int j = 0; j < 4; ++j) {
    int o  = j * 8192 + tid * 16;
    int op = swz(o);
    int r  = op >> 7;
    int kh = (op & 127) >> 1;
    int gr = rowBase + r;
    catH[j] = er + (size_t)pidx[2 * gr]     * 1024 + kh;
    catT[j] = er + (size_t)pidx[2 * gr + 1] * 1024 + kh;
  }

  f32x16 accU[2][2] = {};
  f32x16 accP[2][2] = {};

  _Float16 *Ac = bufA[0], *An = bufA[1], *Af = bufA[2];
  _Float16 *Bc = bufB[0], *Bn = bufB[1], *Bf = bufB[2];

  // prologue: stage tiles 0 and 1 (union)
  stage_tile<4>(Auf, 2048, rowBase, 0,  Ac, tid);
  stage_tile<2>(Btu, 2048, colBase, 0,  Bc, tid);
  stage_tile<4>(Auf, 2048, rowBase, 64, An, tid);
  stage_tile<2>(Btu, 2048, colBase, 64, Bn, tid);

#define TILE_BODY(ACC)                                                          \
  do {                                                                          \
    if (t < NT - 1) asm volatile("s_waitcnt vmcnt(6)" ::: "memory");            \
    else            asm volatile("s_waitcnt vmcnt(0)" ::: "memory");            \
    __builtin_amdgcn_s_barrier();                                               \
    if (t + 2 < NT) {                                                           \
      const int tt = t + 2;                                                     \
      if (tt < NTU) { stage_tile<4>(Auf,  2048, rowBase, tt * 64, Af, tid);     \
                      stage_tile<2>(Btu,  2048, colBase, tt * 64, Bf, tid); }   \
      else {                                                                    \
        const int ktp  = (tt - NTU) * 64;                                       \
        const bool tail = ktp >= 512;                                           \
        char* AfB = reinterpret_cast<char*>(Af);                                \
        _Pragma("unroll") for (int j = 0; j < 4; ++j) {                         \
          int o = j * 8192 + tid * 16;                                          \
          const _Float16* src = (tail ? catT[j] : catH[j]) + ktp;               \
          gload_lds16(src, AfB + (o - lane * 16));                              \
        }                                                                       \
        stage_tile<2>(Btc, 1024, colBase, ktp, Bf, tid);                        \
      }                                                                         \
    }                                                                           \
    const char* aB = reinterpret_cast<const char*>(Ac) + aoff;                  \
    const char* bB = reinterpret_cast<const char*>(Bc) + boff;                  \
    _Pragma("unroll") for (int ks = 0; ks < 4; ++ks) {                          \
      f16x8 a0 = *reinterpret_cast<const f16x8*>(aB + 0 * 4096 + kk[ks]);       \
      f16x8 a1 = *reinterpret_cast<const f16x8*>(aB + 1 * 4096 + kk[ks]);       \
      f16x8 b0 = *reinterpret_cast<const f16x8*>(bB + 0 * 4096 + kk[ks]);       \
      f16x8 b1 = *reinterpret_cast<const f16x8*>(bB + 1 * 4096 + kk[ks]);       \
      ACC[0][0] = __builtin_amdgcn_mfma_f32_32x32x16_f16(a0, b0, ACC[0][0], 0, 0, 0); \
      ACC[0][1] = __builtin_amdgcn_mfma_f32_32x32x16_f16(a0, b1, ACC[0][1], 0, 0, 0); \
      ACC[1][0] = __builtin_amdgcn_mfma_f32_32x32x16_f16(a1, b0, ACC[1][0], 0, 0, 0); \
      ACC[1][1] = __builtin_amdgcn_mfma_f32_32x32x16_f16(a1, b1, ACC[1][1], 0, 0, 0); \
    }                                                                           \
    _Float16* tA = Ac; Ac = An; An = Af; Af = tA;                               \
    _Float16* tB = Bc; Bc = Bn; Bn = Bf; Bf = tB;                               \
  } while (0)

  for (int t = 0; t < NTU; ++t) TILE_BODY(accU);
  for (int t = NTU; t < NT; ++t) TILE_BODY(accP);
#undef TILE_BODY

  // ---------------- epilogue ----------------
  // C/D 32x32 layout: col = lane&31, row = (reg&3) + 8*(reg>>2) + 4*(lane>>5)
#pragma unroll
  for (int n = 0; n < 2; ++n) {
    const int col = colBase + wc * 64 + n * 32 + l31;
    const float bc = bcat[col], bu = bup[col];
#pragma unroll
    for (int m = 0; m < 2; ++m) {
      const int row0 = rowBase + wr * 64 + m * 32 + lh * 4;
#pragma unroll
      for (int i = 0; i < 16; ++i) {
        const int r = row0 + (i & 3) + 8 * (i >> 2);
        out[(size_t)r * 4096 + col] = (accP[m][n][i] + bc) * (accU[m][n][i] + bu);
      }
    }
  }
}

// ---------------------------------------------------------------------------
extern "C" void kernel_launch(void* const* d_in, const int* in_sizes, int n_in,
                              void* d_out, int out_size, void* d_ws, size_t ws_size,
                              hipStream_t stream)
{
  const float* edge_ctx = (const float*)d_in[0];
  const int*   pair_idx = (const int*)d_in[1];
  const float* uf       = (const float*)d_in[2];
  const float* Wpe      = (const float*)d_in[3];
  const float* bpe      = (const float*)d_in[4];
  const float* Wpc      = (const float*)d_in[5];
  const float* bpc      = (const float*)d_in[6];
  const float* Wup      = (const float*)d_in[7];
  const float* bup      = (const float*)d_in[8];
  float* out = (float*)d_out;

  char* ws = (char*)d_ws;
  _Float16* edge_rep = (_Float16*)ws;                                // 2.6 MB region
  _Float16* Auf  = (_Float16*)(ws + 5242880);                        // 256 MB
  _Float16* Btc  = (_Float16*)(ws + 5242880 + 268435456);            //   8 MB
  _Float16* Btu  = (_Float16*)(ws + 5242880 + 268435456 + 8388608);  //  16 MB

  (void)hipFuncSetAttribute((const void*)k_main,
                            hipFuncAttributeMaxDynamicSharedMemorySize, 147456);

  k_pre<<<68768, 256, 0, stream>>>(uf, Auf, Wpc, Btc, Wup, Btu,
                                   edge_ctx, Wpe, bpe, edge_rep);
  k_main<<<8192, 512, 147456, stream>>>(edge_rep, pair_idx, Auf, Btc, Btu,
                                        bpc, bup, out);
}

// Round 14
// 2036.546 us; speedup vs baseline: 1.2894x; 1.0080x over previous
//
#include <hip/hip_runtime.h>
#include <hip/hip_bf16.h>
#include <stdint.h>

typedef _Float16 f16x8 __attribute__((ext_vector_type(8)));
typedef _Float16 f16x4 __attribute__((ext_vector_type(4)));
typedef float    f32x4 __attribute__((ext_vector_type(4)));
typedef float    f32x16 __attribute__((ext_vector_type(16)));

#define NT  48
#define NTU 32

// ---------------------------------------------------------------------------
// global->LDS direct load, 16B per lane; LDS dest = wave-uniform base + lane*16
// ---------------------------------------------------------------------------
__device__ __forceinline__ void gload_lds16(const void* g, void* l) {
  __builtin_amdgcn_global_load_lds(
      reinterpret_cast<const __attribute__((address_space(1))) void*>(
          reinterpret_cast<uintptr_t>(g)),
      reinterpret_cast<__attribute__((address_space(3))) void*>(
          reinterpret_cast<uintptr_t>(l)),
      16, 0, 0);
}

// XOR swizzle within each 128B row: key = (row&7) ^ (row bit4 -> bit2).
// r13 had key=(row&7) only -> lanes 16 apart hit the same bank group
// (2.01e8 conflicts). Adding row bit 4 into offset bit 6 breaks that pairing.
__device__ __forceinline__ int swz(int o) {
  return o ^ ((o >> 3) & 0x70) ^ ((o >> 5) & 0x40);
}

// ---------------------------------------------------------------------------
// merged prepass kernel (r10-verified), role-split by blockIdx:
//   [0, 65536)      : cvt union_features f32 -> f16
//   [65536, 66560)  : transpose Wpc -> Btc row-major (N x K)
//   [66560, 68608)  : transpose Wup -> Btu row-major
//   [68608, 68768)  : edge_rep = f16(relu(edge_ctx @ Wpe + bpe))
// ---------------------------------------------------------------------------
__global__ __launch_bounds__(256) void k_pre(
    const float* __restrict__ uf,  _Float16* __restrict__ Auf,
    const float* __restrict__ Wpc, _Float16* __restrict__ Btc,
    const float* __restrict__ Wup, _Float16* __restrict__ Btu,
    const float* __restrict__ ec,  const float* __restrict__ Wpe,
    const float* __restrict__ bpe, _Float16* __restrict__ er)
{
  __shared__ float lds_f[64 * 65];
  const int b = blockIdx.x;
  const int t = threadIdx.x;

  if (b < 65536) {
    const size_t g = (size_t)b * 256 + t;
    const f32x4* p = reinterpret_cast<const f32x4*>(uf) + g * 2;
    f32x4 v0 = p[0], v1 = p[1];
    f16x8 h;
    h[0] = (_Float16)v0[0]; h[1] = (_Float16)v0[1];
    h[2] = (_Float16)v0[2]; h[3] = (_Float16)v0[3];
    h[4] = (_Float16)v1[0]; h[5] = (_Float16)v1[1];
    h[6] = (_Float16)v1[2]; h[7] = (_Float16)v1[3];
    *(reinterpret_cast<f16x8*>(Auf) + g) = h;
    return;
  }

  if (b < 68608) {
    const float* W; _Float16* Wt; int K, bid2;
    if (b < 66560) { W = Wpc; Wt = Btc; K = 1024; bid2 = b - 65536; }
    else           { W = Wup; Wt = Btu; K = 2048; bid2 = b - 66560; }
    const int ntn = 64;
    const int kt = bid2 / ntn, nt = bid2 % ntn;
    const int tx = t & 63, ty = t >> 6;
    const int k0 = kt * 64, n0 = nt * 64;
#pragma unroll
    for (int j = 0; j < 16; ++j) {
      int kr = j * 4 + ty;
      lds_f[kr * 65 + tx] = W[(size_t)(k0 + kr) * 4096 + n0 + tx];
    }
    __syncthreads();
#pragma unroll
    for (int j = 0; j < 16; ++j) {
      int nr = j * 4 + ty;
      Wt[(size_t)(n0 + nr) * K + k0 + tx] = (_Float16)lds_f[tx * 65 + nr];
    }
    return;
  }

  {
    const int rb = (b - 68608) * 8;
    float* sec = lds_f;
#pragma unroll
    for (int j = 0; j < 16; ++j)
      sec[j * 256 + t] = ec[(size_t)rb * 512 + j * 256 + t];
    __syncthreads();

    const int c4 = t * 4;
    f32x4 acc[8];
#pragma unroll
    for (int r = 0; r < 8; ++r) acc[r] = f32x4{0.f, 0.f, 0.f, 0.f};
    for (int k = 0; k < 512; ++k) {
      f32x4 w = *reinterpret_cast<const f32x4*>(Wpe + (size_t)k * 1024 + c4);
#pragma unroll
      for (int r = 0; r < 8; ++r) acc[r] += sec[r * 512 + k] * w;
    }
    f32x4 bb = *reinterpret_cast<const f32x4*>(bpe + c4);
#pragma unroll
    for (int r = 0; r < 8; ++r) {
      f32x4 o = acc[r] + bb;
      f16x4 h;
#pragma unroll
      for (int i = 0; i < 4; ++i) h[i] = (_Float16)(o[i] > 0.f ? o[i] : 0.f);
      *reinterpret_cast<f16x4*>(er + (size_t)(rb + r) * 1024 + c4) = h;
    }
  }
}

// ---------------------------------------------------------------------------
// A/B staging: NI chunks of 8KB; linear LDS dest, source pre-swizzled.
// ---------------------------------------------------------------------------
template<int NI>
__device__ __forceinline__ void stage_tile(const _Float16* __restrict__ src, int ldk,
                                           int rcBase, int kt, _Float16* sbuf, int tid)
{
#pragma unroll
  for (int j = 0; j < NI; ++j) {
    int o  = j * 8192 + tid * 16;
    int op = swz(o);
    int r  = op >> 7;
    int kh = (op & 127) >> 1;
    gload_lds16(src + (size_t)(rcBase + r) * ldk + kt + kh,
                sbuf + (o - (tid & 63) * 16) / 2);
  }
}

// ---------------------------------------------------------------------------
// main fused dual-GEMM: out = (Acat@Wc^T + bc) * (Auf@Wu^T + bu)
// BM=256 BN=128 BK=64, 512 thr = 8 waves (4x2), wave tile 64x64.
// r13 structure (3-buffer, depth-2, vmcnt(6), ONE barrier/tile, XCD-col map,
// unfenced interior, fused cat-gather, 32x32x16 MFMA) with the extended
// bank-swizzle (row bit4 -> offset bit6) to kill the lane-pair conflicts.
// ---------------------------------------------------------------------------
__global__ __launch_bounds__(512, 2) void k_main(
    const _Float16* __restrict__ er,  const int* __restrict__ pidx,
    const _Float16* __restrict__ Auf,
    const _Float16* __restrict__ Btc, const _Float16* __restrict__ Btu,
    const float* __restrict__ bcat, const float* __restrict__ bup,
    float* __restrict__ out)
{
  extern __shared__ char smem[];                    // 144 KiB dynamic
  _Float16* bufA[3] = { reinterpret_cast<_Float16*>(smem),
                        reinterpret_cast<_Float16*>(smem + 32768),
                        reinterpret_cast<_Float16*>(smem + 65536) };
  _Float16* bufB[3] = { reinterpret_cast<_Float16*>(smem + 98304),
                        reinterpret_cast<_Float16*>(smem + 98304 + 16384),
                        reinterpret_cast<_Float16*>(smem + 98304 + 32768) };

  const int tid  = threadIdx.x;
  const int lane = tid & 63;
  const int l31  = lane & 31, lh = lane >> 5;
  const int wid  = tid >> 6, wr = wid >> 1, wc = wid & 1;      // 4x2 wave grid

  // XCD column-ownership mapping: xcd = bid&7 owns cols [xcd*512, xcd*512+512)
  const int bid = blockIdx.x;
  const int xcd = bid & 7;
  const int seq = bid >> 3;
  const int rowBase = (seq >> 2) * 256;
  const int colBase = (xcd * 4 + (seq & 3)) * 128;

  // swizzled LDS read offsets for 32x32x16 fragments.
  // row (mod 32) == l31 for both A and B (m*32 / n*32 / w*64 don't touch
  // bits 0-4), so key = (l31&7)<<4 ^ (l31 bit4 -> bit6).
  const int key32 = ((l31 & 7) << 4) ^ ((l31 & 16) << 2);
  int kk[4];
#pragma unroll
  for (int ks = 0; ks < 4; ++ks) kk[ks] = (((ks * 2 + lh) << 4) ^ key32);
  const int aoff = (wr * 64 + l31) * 128;
  const int boff = (wc * 64 + l31) * 128;

  // fused-gather source pointers for cat A staging
  const _Float16* catH[4];
  const _Float16* catT[4];
#pragma unroll
  for (int j = 0; j < 4; ++j) {
    int o  = j * 8192 + tid * 16;
    int op = swz(o);
    int r  = op >> 7;
    int kh = (op & 127) >> 1;
    int gr = rowBase + r;
    catH[j] = er + (size_t)pidx[2 * gr]     * 1024 + kh;
    catT[j] = er + (size_t)pidx[2 * gr + 1] * 1024 + kh;
  }

  f32x16 accU[2][2] = {};
  f32x16 accP[2][2] = {};

  _Float16 *Ac = bufA[0], *An = bufA[1], *Af = bufA[2];
  _Float16 *Bc = bufB[0], *Bn = bufB[1], *Bf = bufB[2];

  // prologue: stage tiles 0 and 1 (union)
  stage_tile<4>(Auf, 2048, rowBase, 0,  Ac, tid);
  stage_tile<2>(Btu, 2048, colBase, 0,  Bc, tid);
  stage_tile<4>(Auf, 2048, rowBase, 64, An, tid);
  stage_tile<2>(Btu, 2048, colBase, 64, Bn, tid);

#define TILE_BODY(ACC)                                                          \
  do {                                                                          \
    if (t < NT - 1) asm volatile("s_waitcnt vmcnt(6)" ::: "memory");            \
    else            asm volatile("s_waitcnt vmcnt(0)" ::: "memory");            \
    __builtin_amdgcn_s_barrier();                                               \
    if (t + 2 < NT) {                                                           \
      const int tt = t + 2;                                                     \
      if (tt < NTU) { stage_tile<4>(Auf,  2048, rowBase, tt * 64, Af, tid);     \
                      stage_tile<2>(Btu,  2048, colBase, tt * 64, Bf, tid); }   \
      else {                                                                    \
        const int ktp  = (tt - NTU) * 64;                                       \
        const bool tail = ktp >= 512;                                           \
        char* AfB = reinterpret_cast<char*>(Af);                                \
        _Pragma("unroll") for (int j = 0; j < 4; ++j) {                         \
          int o = j * 8192 + tid * 16;                                          \
          const _Float16* src = (tail ? catT[j] : catH[j]) + ktp;               \
          gload_lds16(src, AfB + (o - lane * 16));                              \
        }                                                                       \
        stage_tile<2>(Btc, 1024, colBase, ktp, Bf, tid);                        \
      }                                                                         \
    }                                                                           \
    const char* aB = reinterpret_cast<const char*>(Ac) + aoff;                  \
    const char* bB = reinterpret_cast<const char*>(Bc) + boff;                  \
    _Pragma("unroll") for (int ks = 0; ks < 4; ++ks) {                          \
      f16x8 a0 = *reinterpret_cast<const f16x8*>(aB + 0 * 4096 + kk[ks]);       \
      f16x8 a1 = *reinterpret_cast<const f16x8*>(aB + 1 * 4096 + kk[ks]);       \
      f16x8 b0 = *reinterpret_cast<const f16x8*>(bB + 0 * 4096 + kk[ks]);       \
      f16x8 b1 = *reinterpret_cast<const f16x8*>(bB + 1 * 4096 + kk[ks]);       \
      ACC[0][0] = __builtin_amdgcn_mfma_f32_32x32x16_f16(a0, b0, ACC[0][0], 0, 0, 0); \
      ACC[0][1] = __builtin_amdgcn_mfma_f32_32x32x16_f16(a0, b1, ACC[0][1], 0, 0, 0); \
      ACC[1][0] = __builtin_amdgcn_mfma_f32_32x32x16_f16(a1, b0, ACC[1][0], 0, 0, 0); \
      ACC[1][1] = __builtin_amdgcn_mfma_f32_32x32x16_f16(a1, b1, ACC[1][1], 0, 0, 0); \
    }                                                                           \
    _Float16* tA = Ac; Ac = An; An = Af; Af = tA;                               \
    _Float16* tB = Bc; Bc = Bn; Bn = Bf; Bf = tB;                               \
  } while (0)

  for (int t = 0; t < NTU; ++t) TILE_BODY(accU);
  for (int t = NTU; t < NT; ++t) TILE_BODY(accP);
#undef TILE_BODY

  // ---------------- epilogue ----------------
  // C/D 32x32 layout: col = lane&31, row = (reg&3) + 8*(reg>>2) + 4*(lane>>5)
#pragma unroll
  for (int n = 0; n < 2; ++n) {
    const int col = colBase + wc * 64 + n * 32 + l31;
    const float bc = bcat[col], bu = bup[col];
#pragma unroll
    for (int m = 0; m < 2; ++m) {
      const int row0 = rowBase + wr * 64 + m * 32 + lh * 4;
#pragma unroll
      for (int i = 0; i < 16; ++i) {
        const int r = row0 + (i & 3) + 8 * (i >> 2);
        out[(size_t)r * 4096 + col] = (accP[m][n][i] + bc) * (accU[m][n][i] + bu);
      }
    }
  }
}

// ---------------------------------------------------------------------------
extern "C" void kernel_launch(void* const* d_in, const int* in_sizes, int n_in,
                              void* d_out, int out_size, void* d_ws, size_t ws_size,
                              hipStream_t stream)
{
  const float* edge_ctx = (const float*)d_in[0];
  const int*   pair_idx = (const int*)d_in[1];
  const float* uf       = (const float*)d_in[2];
  const float* Wpe      = (const float*)d_in[3];
  const float* bpe      = (const float*)d_in[4];
  const float* Wpc      = (const float*)d_in[5];
  const float* bpc      = (const float*)d_in[6];
  const float* Wup      = (const float*)d_in[7];
  const float* bup      = (const float*)d_in[8];
  float* out = (float*)d_out;

  char* ws = (char*)d_ws;
  _Float16* edge_rep = (_Float16*)ws;                                // 2.6 MB region
  _Float16* Auf  = (_Float16*)(ws + 5242880);                        // 256 MB
  _Float16* Btc  = (_Float16*)(ws + 5242880 + 268435456);            //   8 MB
  _Float16* Btu  = (_Float16*)(ws + 5242880 + 268435456 + 8388608);  //  16 MB

  (void)hipFuncSetAttribute((const void*)k_main,
                            hipFuncAttributeMaxDynamicSharedMemorySize, 147456);

  k_pre<<<68768, 256, 0, stream>>>(uf, Auf, Wpc, Btc, Wup, Btu,
                                   edge_ctx, Wpe, bpe, edge_rep);
  k_main<<<8192, 512, 147456, stream>>>(edge_rep, pair_idx, Auf, Btc, Btu,
                                        bpc, bup, out);
}

// Round 15
// 1925.569 us; speedup vs baseline: 1.3637x; 1.0576x over previous
//
#include <hip/hip_runtime.h>
#include <hip/hip_bf16.h>
#include <stdint.h>

typedef _Float16 f16x8 __attribute__((ext_vector_type(8)));
typedef _Float16 f16x4 __attribute__((ext_vector_type(4)));
typedef float    f32x4 __attribute__((ext_vector_type(4)));

#define NT  48
#define NTU 32

// ---------------------------------------------------------------------------
// global->LDS direct load, 16B per lane; LDS dest = wave-uniform base + lane*16
// ---------------------------------------------------------------------------
__device__ __forceinline__ void gload_lds16(const void* g, void* l) {
  __builtin_amdgcn_global_load_lds(
      reinterpret_cast<const __attribute__((address_space(1))) void*>(
          reinterpret_cast<uintptr_t>(g)),
      reinterpret_cast<__attribute__((address_space(3))) void*>(
          reinterpret_cast<uintptr_t>(l)),
      16, 0, 0);
}

// XOR swizzle within each 128B row, keyed off row&7 (bits 7-9 of byte offset).
__device__ __forceinline__ int swz(int o) { return o ^ ((o >> 3) & 0x70); }

// ---------------------------------------------------------------------------
// merged prepass kernel, role-split by blockIdx (edge FIRST to cut the tail):
//   [0, 160)            : edge_rep = f16(relu(edge_ctx @ Wpe + bpe))
//   [160, 65696)        : cvt union_features f32 -> f16
//   [65696, 66720)      : transpose Wpc -> Btc row-major (N x K)
//   [66720, 68768)      : transpose Wup -> Btu row-major
// ---------------------------------------------------------------------------
__global__ __launch_bounds__(256) void k_pre(
    const float* __restrict__ uf,  _Float16* __restrict__ Auf,
    const float* __restrict__ Wpc, _Float16* __restrict__ Btc,
    const float* __restrict__ Wup, _Float16* __restrict__ Btu,
    const float* __restrict__ ec,  const float* __restrict__ Wpe,
    const float* __restrict__ bpe, _Float16* __restrict__ er)
{
  __shared__ float lds_f[64 * 65];
  const int b = blockIdx.x;
  const int t = threadIdx.x;

  if (b < 160) {
    // ---- edge: 8 rows per block, fp32 accumulate, relu, f16 store ----
    const int rb = b * 8;
    float* sec = lds_f;   // 8*512 floats = 16KB
#pragma unroll
    for (int j = 0; j < 16; ++j)
      sec[j * 256 + t] = ec[(size_t)rb * 512 + j * 256 + t];
    __syncthreads();

    const int c4 = t * 4;
    f32x4 acc[8];
#pragma unroll
    for (int r = 0; r < 8; ++r) acc[r] = f32x4{0.f, 0.f, 0.f, 0.f};
    for (int k = 0; k < 512; ++k) {
      f32x4 w = *reinterpret_cast<const f32x4*>(Wpe + (size_t)k * 1024 + c4);
#pragma unroll
      for (int r = 0; r < 8; ++r) acc[r] += sec[r * 512 + k] * w;
    }
    f32x4 bb = *reinterpret_cast<const f32x4*>(bpe + c4);
#pragma unroll
    for (int r = 0; r < 8; ++r) {
      f32x4 o = acc[r] + bb;
      f16x4 h;
#pragma unroll
      for (int i = 0; i < 4; ++i) h[i] = (_Float16)(o[i] > 0.f ? o[i] : 0.f);
      *reinterpret_cast<f16x4*>(er + (size_t)(rb + r) * 1024 + c4) = h;
    }
    return;
  }

  if (b < 65696) {
    // ---- cvt: 8 f32 -> 8 f16 per thread ----
    const size_t g = (size_t)(b - 160) * 256 + t;
    const f32x4* p = reinterpret_cast<const f32x4*>(uf) + g * 2;
    f32x4 v0 = p[0], v1 = p[1];
    f16x8 h;
    h[0] = (_Float16)v0[0]; h[1] = (_Float16)v0[1];
    h[2] = (_Float16)v0[2]; h[3] = (_Float16)v0[3];
    h[4] = (_Float16)v1[0]; h[5] = (_Float16)v1[1];
    h[6] = (_Float16)v1[2]; h[7] = (_Float16)v1[3];
    *(reinterpret_cast<f16x8*>(Auf) + g) = h;
    return;
  }

  // ---- weight transpose: Wt[n][k] = f16(W[k][n]) ----
  {
    const float* W; _Float16* Wt; int K, bid2;
    if (b < 66720) { W = Wpc; Wt = Btc; K = 1024; bid2 = b - 65696; }
    else           { W = Wup; Wt = Btu; K = 2048; bid2 = b - 66720; }
    const int ntn = 64;
    const int kt = bid2 / ntn, nt = bid2 % ntn;
    const int tx = t & 63, ty = t >> 6;
    const int k0 = kt * 64, n0 = nt * 64;
#pragma unroll
    for (int j = 0; j < 16; ++j) {
      int kr = j * 4 + ty;
      lds_f[kr * 65 + tx] = W[(size_t)(k0 + kr) * 4096 + n0 + tx];
    }
    __syncthreads();
#pragma unroll
    for (int j = 0; j < 16; ++j) {
      int nr = j * 4 + ty;
      Wt[(size_t)(n0 + nr) * K + k0 + tx] = (_Float16)lds_f[tx * 65 + nr];
    }
  }
}

// ---------------------------------------------------------------------------
// staging: NI chunks of 8KB; linear LDS dest, source pre-swizzled. (verified)
// ---------------------------------------------------------------------------
template<int NI>
__device__ __forceinline__ void stage_tile(const _Float16* __restrict__ src, int ldk,
                                           int rcBase, int kt, _Float16* sbuf, int tid)
{
#pragma unroll
  for (int j = 0; j < NI; ++j) {
    int o  = j * 8192 + tid * 16;
    int op = swz(o);
    int r  = op >> 7;
    int kh = (op & 127) >> 1;
    gload_lds16(src + (size_t)(rcBase + r) * ldk + kt + kh,
                sbuf + (o - (tid & 63) * 16) / 2);
  }
}

// ---------------------------------------------------------------------------
// main fused dual-GEMM: out = (Acat@Wc^T + bc) * (Auf@Wu^T + bu)
// BM=256 BN=128 BK=64, 512 thr = 8 waves (4x2), wave tile 64x64.
// Best-measured configuration (r10): 3-buffer, depth-2 prefetch, counted
// vmcnt(6), ONE barrier/tile, XCD column-ownership map, unfenced interior,
// cat-gather fused into staging. 16x16x32 MFMA (0 bank conflicts).
// Unified 48-tile K loop: tiles 0..31 = union (K=2048), 32..47 = cat (K=1024).
// ---------------------------------------------------------------------------
__global__ __launch_bounds__(512, 2) void k_main(
    const _Float16* __restrict__ er,  const int* __restrict__ pidx,
    const _Float16* __restrict__ Auf,
    const _Float16* __restrict__ Btc, const _Float16* __restrict__ Btu,
    const float* __restrict__ bcat, const float* __restrict__ bup,
    float* __restrict__ out)
{
  extern __shared__ char smem[];                    // 144 KiB dynamic
  _Float16* bufA[3] = { reinterpret_cast<_Float16*>(smem),
                        reinterpret_cast<_Float16*>(smem + 32768),
                        reinterpret_cast<_Float16*>(smem + 65536) };
  _Float16* bufB[3] = { reinterpret_cast<_Float16*>(smem + 98304),
                        reinterpret_cast<_Float16*>(smem + 98304 + 16384),
                        reinterpret_cast<_Float16*>(smem + 98304 + 32768) };

  const int tid  = threadIdx.x;
  const int lane = tid & 63, lr = lane & 15, lg = lane >> 4;
  const int wid  = tid >> 6, wr = wid >> 1, wc = wid & 1;      // 4x2 wave grid

  // XCD column-ownership mapping: xcd = bid&7 owns cols [xcd*512, xcd*512+512)
  const int bid = blockIdx.x;
  const int xcd = bid & 7;
  const int seq = bid >> 3;
  const int rowBase = (seq >> 2) * 256;
  const int colBase = (xcd * 4 + (seq & 3)) * 128;

  // per-thread swizzled LDS read offsets
  const int key  = (lr & 7) << 4;
  int kb[2];
  kb[0] = (lg * 16) ^ key;
  kb[1] = (64 + lg * 16) ^ key;
  const int aoff = (wr * 64 + lr) * 128;
  const int boff = (wc * 64 + lr) * 128;

  // fused-gather source pointers for cat A staging
  const _Float16* catH[4];
  const _Float16* catT[4];
#pragma unroll
  for (int j = 0; j < 4; ++j) {
    int o  = j * 8192 + tid * 16;
    int op = swz(o);
    int r  = op >> 7;
    int kh = (op & 127) >> 1;
    int gr = rowBase + r;
    catH[j] = er + (size_t)pidx[2 * gr]     * 1024 + kh;
    catT[j] = er + (size_t)pidx[2 * gr + 1] * 1024 + kh;
  }

  f16x8 af[4][2], bf[4][2];
  f32x4 accU[4][4] = {};
  f32x4 accP[4][4] = {};

  _Float16 *Ac = bufA[0], *An = bufA[1], *Af = bufA[2];
  _Float16 *Bc = bufB[0], *Bn = bufB[1], *Bf = bufB[2];

  // prologue: stage tiles 0 and 1 (union)
  stage_tile<4>(Auf, 2048, rowBase, 0,  Ac, tid);
  stage_tile<2>(Btu, 2048, colBase, 0,  Bc, tid);
  stage_tile<4>(Auf, 2048, rowBase, 64, An, tid);
  stage_tile<2>(Btu, 2048, colBase, 64, Bn, tid);

#define TILE_BODY(ACC)                                                          \
  do {                                                                          \
    if (t < NT - 1) asm volatile("s_waitcnt vmcnt(6)" ::: "memory");            \
    else            asm volatile("s_waitcnt vmcnt(0)" ::: "memory");            \
    __builtin_amdgcn_s_barrier();                                               \
    if (t + 2 < NT) {                                                           \
      const int tt = t + 2;                                                     \
      if (tt < NTU) { stage_tile<4>(Auf,  2048, rowBase, tt * 64, Af, tid);     \
                      stage_tile<2>(Btu,  2048, colBase, tt * 64, Bf, tid); }   \
      else {                                                                    \
        const int ktp  = (tt - NTU) * 64;                                       \
        const bool tail = ktp >= 512;                                           \
        char* AfB = reinterpret_cast<char*>(Af);                                \
        _Pragma("unroll") for (int j = 0; j < 4; ++j) {                         \
          int o = j * 8192 + tid * 16;                                          \
          const _Float16* src = (tail ? catT[j] : catH[j]) + ktp;               \
          gload_lds16(src, AfB + (o - lane * 16));                              \
        }                                                                       \
        stage_tile<2>(Btc, 1024, colBase, ktp, Bf, tid);                        \
      }                                                                         \
    }                                                                           \
    const char* aB = reinterpret_cast<const char*>(Ac) + aoff;                  \
    const char* bB = reinterpret_cast<const char*>(Bc) + boff;                  \
    /* unfenced: compiler interleaves read issue, addr VALU and MFMA */         \
    _Pragma("unroll") for (int m = 0; m < 4; ++m)                               \
      _Pragma("unroll") for (int ks = 0; ks < 2; ++ks)                          \
        af[m][ks] = *reinterpret_cast<const f16x8*>(aB + m * 2048 + kb[ks]);    \
    _Pragma("unroll") for (int n = 0; n < 4; ++n)                               \
      _Pragma("unroll") for (int ks = 0; ks < 2; ++ks)                          \
        bf[n][ks] = *reinterpret_cast<const f16x8*>(bB + n * 2048 + kb[ks]);    \
    _Pragma("unroll") for (int m = 0; m < 4; ++m)                               \
      _Pragma("unroll") for (int n = 0; n < 4; ++n)                             \
        _Pragma("unroll") for (int ks = 0; ks < 2; ++ks)                        \
          ACC[m][n] = __builtin_amdgcn_mfma_f32_16x16x32_f16(af[m][ks], bf[n][ks], ACC[m][n], 0, 0, 0); \
    _Float16* tA = Ac; Ac = An; An = Af; Af = tA;                               \
    _Float16* tB = Bc; Bc = Bn; Bn = Bf; Bf = tB;                               \
  } while (0)

  for (int t = 0; t < NTU; ++t) TILE_BODY(accU);
  for (int t = NTU; t < NT; ++t) TILE_BODY(accP);
#undef TILE_BODY

  // ---------------- epilogue ----------------
#pragma unroll
  for (int n = 0; n < 4; ++n) {
    const int col = colBase + wc * 64 + n * 16 + lr;
    const float bc = bcat[col], bu = bup[col];
#pragma unroll
    for (int m = 0; m < 4; ++m) {
      const int row0 = rowBase + wr * 64 + m * 16 + lg * 4;
#pragma unroll
      for (int i = 0; i < 4; ++i)
        out[(size_t)(row0 + i) * 4096 + col] =
            (accP[m][n][i] + bc) * (accU[m][n][i] + bu);
    }
  }
}

// ---------------------------------------------------------------------------
extern "C" void kernel_launch(void* const* d_in, const int* in_sizes, int n_in,
                              void* d_out, int out_size, void* d_ws, size_t ws_size,
                              hipStream_t stream)
{
  const float* edge_ctx = (const float*)d_in[0];
  const int*   pair_idx = (const int*)d_in[1];
  const float* uf       = (const float*)d_in[2];
  const float* Wpe      = (const float*)d_in[3];
  const float* bpe      = (const float*)d_in[4];
  const float* Wpc      = (const float*)d_in[5];
  const float* bpc      = (const float*)d_in[6];
  const float* Wup      = (const float*)d_in[7];
  const float* bup      = (const float*)d_in[8];
  float* out = (float*)d_out;

  char* ws = (char*)d_ws;
  _Float16* edge_rep = (_Float16*)ws;                                // 2.6 MB region
  _Float16* Auf  = (_Float16*)(ws + 5242880);                        // 256 MB
  _Float16* Btc  = (_Float16*)(ws + 5242880 + 268435456);            //   8 MB
  _Float16* Btu  = (_Float16*)(ws + 5242880 + 268435456 + 8388608);  //  16 MB

  (void)hipFuncSetAttribute((const void*)k_main,
                            hipFuncAttributeMaxDynamicSharedMemorySize, 147456);

  // merged prepass: edge (160) + cvt (65536) + wt_c (1024) + wt_u (2048)
  k_pre<<<68768, 256, 0, stream>>>(uf, Auf, Wpc, Btc, Wup, Btu,
                                   edge_ctx, Wpe, bpe, edge_rep);
  k_main<<<8192, 512, 147456, stream>>>(edge_rep, pair_idx, Auf, Btc, Btu,
                                        bpc, bup, out);
}